// Round 9
// baseline (146.771 us; speedup 1.0000x reference)
//
#include <hip/hip_runtime.h>
#include <stdint.h>

// SelfAttention: B=4, T=2048, EMB=1024, causal + key padding (last 256 keys)
#define TB 2048
#define DD 1024

typedef __bf16 bf16x8 __attribute__((ext_vector_type(8)));
typedef float  f32x16 __attribute__((ext_vector_type(16)));
typedef int    int4v  __attribute__((ext_vector_type(4)));
typedef unsigned u32;

__device__ __forceinline__ u32 pack2(float hi, float lo) {
  return (__float_as_uint(hi) & 0xffff0000u) | (__float_as_uint(lo) >> 16);
}
__device__ __forceinline__ bf16x8 pack8(const float f[8]) {
  int4v w;
  w.x = (int)pack2(f[1], f[0]);
  w.y = (int)pack2(f[3], f[2]);
  w.z = (int)pack2(f[5], f[4]);
  w.w = (int)pack2(f[7], f[6]);
  return __builtin_bit_cast(bf16x8, w);
}

// ===================== fused pre-pass: Q,K,V -> bf16 fragments =====================
__global__ __launch_bounds__(256)
void conv_all(const float* __restrict__ Q, const float* __restrict__ K,
              const float* __restrict__ V,
              unsigned short* __restrict__ Qf, unsigned short* __restrict__ Kf,
              unsigned short* __restrict__ Vf) {
  __shared__ __align__(16) float t[64 * 260];
  if (blockIdx.x < 512) {
    const int isQ = blockIdx.x >> 8;
    const int bid = blockIdx.x & 255;
    const float* src0 = isQ ? Q : K;
    unsigned short* dst0 = isQ ? Qf : Kf;
    const float scl = isQ ? 0.03125f : 1.0f;
    const int b  = bid >> 6;
    const int kt = bid & 63;
    const int lt  = threadIdx.x & 63;
    const int row = lt & 31, hi = lt >> 5;
    const int wv  = threadIdx.x >> 6;
    const float* src = src0 + ((size_t)(b * TB + kt * 32 + row)) * DD + hi * 8;
    unsigned short* dst = dst0 + ((size_t)(b * 64 + kt) * 64) * 512 + lt * 8;
    #pragma unroll
    for (int i = 0; i < 16; ++i) {
      const int ds = wv + 4 * i;
      const float4 a = *(const float4*)(src + ds * 16);
      const float4 c = *(const float4*)(src + ds * 16 + 4);
      const float f[8] = {a.x*scl, a.y*scl, a.z*scl, a.w*scl,
                          c.x*scl, c.y*scl, c.z*scl, c.w*scl};
      *(int4v*)(dst + (size_t)ds * 512) = __builtin_bit_cast(int4v, pack8(f));
    }
  } else {
    const int bid = blockIdx.x - 512;
    const int b   = bid >> 7;
    const int kb  = (bid >> 2) & 31;
    const int db  = bid & 3;
    const int k0 = kb * 64, d0 = db * 256;
    {
      const int f = threadIdx.x & 63;
      const int r0 = threadIdx.x >> 6;
      #pragma unroll
      for (int i = 0; i < 16; ++i) {
        const int kloc = r0 + 4 * i;
        const float4 v4 = *(const float4*)(V + ((size_t)(b * TB + k0 + kloc)) * DD + d0 + f * 4);
        *(float4*)(t + kloc * 260 + f * 4) = v4;
      }
    }
    __syncthreads();
    const int lt  = threadIdx.x & 63;
    const int lo5 = lt & 31, hi = lt >> 5;
    const int kk  = threadIdx.x >> 6;
    #pragma unroll
    for (int dd = 0; dd < 8; ++dd) {
      float f[8];
      #pragma unroll
      for (int j = 0; j < 8; ++j)
        f[j] = t[(kk * 16 + hi * 8 + j) * 260 + dd * 32 + lo5];
      unsigned short* dst = Vf +
          (((size_t)(b * 32 + (d0 >> 5) + dd) * 128 + (k0 >> 4) + kk) * 64 + lt) * 8;
      *(int4v*)dst = __builtin_bit_cast(int4v, pack8(f));
    }
  }
}

// ===================== main kernel v8: v6 + 8-deep K/V software prefetch ==========
// Grid 512: block = (b, qt 0..63, key-half h), heaviest qt dispatched first.
// QK: wave w owns keys [k0+32w, +32), full d; Q from LDS, K streamed (8-deep pf).
// PV: wave w owns d slice [128w, +128); P single-phase 16KB LDS; V 8-deep pf.
__global__ __launch_bounds__(512, 2)
void fa_fwd_f32_v8(const unsigned short* __restrict__ Qf, const int* __restrict__ AM,
                   const unsigned short* __restrict__ Kf, const unsigned short* __restrict__ Vf,
                   unsigned short* __restrict__ OA, unsigned short* __restrict__ OB,
                   float* __restrict__ ML)
{
  __shared__ __align__(16) unsigned short lds_Q[64 * 64 * 8];   // 65536 B [ds][lane][8]
  __shared__ __align__(16) unsigned short lds_P[16 * 64 * 8];   // 16384 B [kc][lane][8]
  __shared__ float lds_red[8][32];                              // 1024 B
  __shared__ unsigned char lds_nib[512];                        // pad-mask nibbles
  __shared__ int lds_tvi;

  const int tid  = threadIdx.x;
  const int w    = tid >> 6;
  const int lane = tid & 63;
  const int lo5  = lane & 31;
  const int hi   = lane >> 5;

  const int bid  = blockIdx.x;
  const int xcd  = bid & 7, slot = bid >> 3;       // slot 0..63
  const int b    = xcd >> 1, x = xcd & 1;
  const int rank = slot >> 1, h = slot & 1;
  const int qt   = 63 - 2 * rank - x;              // heavy-first LPT
  const int q0   = qt << 5;

  // ---- stage Q tile (frag order, contiguous) + pad-mask nibbles ----
  {
    const char* qsrc = (const char*)Qf + ((size_t)(b * 64 + qt)) * 65536 + tid * 16;
    #pragma unroll
    for (int i = 0; i < 8; ++i)
      *(int4v*)((char*)lds_Q + tid * 16 + i * 8192) = *(const int4v*)(qsrc + (size_t)i * 8192);
  }
  if (tid == 0) lds_tvi = 0;
  __syncthreads();
  {
    const int4v mi = *(const int4v*)(AM + b * TB + 4 * tid);
    const unsigned char nib = (mi.x?1:0)|(mi.y?2:0)|(mi.z?4:0)|(mi.w?8:0);
    lds_nib[tid] = nib;
    if (nib) atomicOr(&lds_tvi, 1 << (tid >> 6));
  }
  __syncthreads();
  const int tvbits = lds_tvi;

  float m = -1e30f, l = 0.f;
  f32x16 oacc[4] = {f32x16{}, f32x16{}, f32x16{}, f32x16{}};

  const char* vb = (const char*)Vf + ((size_t)(b * 32 + 4 * w)) * 131072 + lane * 16;
  const int q = q0 + lo5;
  const int diag_kt = qt >> 3;

  const int nkt = diag_kt + 1;
  for (int kt = h; kt < nkt; kt += 2) {
    if (!(tvbits & (1 << kt))) continue;
    const int k0 = kt << 8;

    // ---- QK^T swapped: S[32 keys(w) x 32 q], full d, 8-deep K prefetch ----
    f32x16 s0{}, s1{};
    {
      const char* kp = (const char*)Kf + ((size_t)(b * 64 + kt * 8 + w)) * 65536 + lane * 16;
      const char* qp = (const char*)lds_Q + lane * 16;
      bf16x8 kbuf[8];
      #pragma unroll
      for (int i = 0; i < 8; ++i)
        kbuf[i] = *(const bf16x8*)(kp + (size_t)i * 1024);
      __builtin_amdgcn_s_setprio(1);
      #pragma unroll
      for (int ds = 0; ds < 64; ++ds) {
        const bf16x8 kf = kbuf[ds & 7];
        if (ds < 56)
          kbuf[ds & 7] = *(const bf16x8*)(kp + (size_t)(ds + 8) * 1024);
        if (ds & 1)
          s1 = __builtin_amdgcn_mfma_f32_32x32x16_bf16(
              kf, *(const bf16x8*)(qp + (size_t)ds * 1024), s1, 0, 0, 0);
        else
          s0 = __builtin_amdgcn_mfma_f32_32x32x16_bf16(
              kf, *(const bf16x8*)(qp + (size_t)ds * 1024), s0, 0, 0, 0);
      }
      __builtin_amdgcn_s_setprio(0);
    }

    // ---- merge chains, mask (fast path off-diagonal), wave max ----
    u32 mw;
    {
      const u32* nw = (const u32*)(lds_nib + 64 * kt + 8 * w);
      const u32 n0 = nw[0], n1 = nw[1];
      mw = (n0 & 0xFu) | ((n0 >> 4) & 0xF0u) | ((n0 >> 8) & 0xF00u) | ((n0 >> 12) & 0xF000u);
      mw |= ((n1 & 0xFu) | ((n1 >> 4) & 0xF0u) | ((n1 >> 8) & 0xF00u) | ((n1 >> 12) & 0xF000u)) << 16;
    }
    float s[16];
    float mx = -1e30f;
    if (kt != diag_kt && mw == 0xffffffffu) {
      #pragma unroll
      for (int r = 0; r < 16; ++r) { s[r] = s0[r] + s1[r]; mx = fmaxf(mx, s[r]); }
    } else {
      #pragma unroll
      for (int r = 0; r < 16; ++r) {
        const int kl = (r & 3) + 8 * (r >> 2) + 4 * hi;
        const bool ok = (((mw >> kl) & 1u) != 0u) && (k0 + 32 * w + kl <= q);
        s[r] = ok ? (s0[r] + s1[r]) : -1e30f;
        mx = fmaxf(mx, s[r]);
      }
    }
    mx = fmaxf(mx, __shfl_xor(mx, 32, 64));
    if (lane < 32) lds_red[w][lo5] = mx;
    __syncthreads();                                   // BAR1: maxes + PV(t-1) done

    float gm = m;
    #pragma unroll
    for (int j = 0; j < 8; ++j) gm = fmaxf(gm, lds_red[j][lo5]);
    const float sc = __expf(m - gm);
    m = gm;
    const float pm = fmaxf(gm, -1e28f);                // all-masked guard
    float ls = 0.f;
    #pragma unroll
    for (int r = 0; r < 16; ++r) { s[r] = __expf(s[r] - pm); ls += s[r]; }
    ls += __shfl_xor(ls, 32, 64);
    l = l * sc + ls;
    #pragma unroll
    for (int nb = 0; nb < 4; ++nb)
      #pragma unroll
      for (int r = 0; r < 16; ++r) oacc[nb][r] *= sc;

    // P^T frag write: wave w owns kc slots 2w, 2w+1 (single phase, all 16 slots)
    {
      #pragma unroll
      for (int c = 0; c < 2; ++c) {
        const u32 pw0 = pack2(s[8*c+1], s[8*c+0]);
        const u32 pw1 = pack2(s[8*c+3], s[8*c+2]);
        const u32 pw2 = pack2(s[8*c+5], s[8*c+4]);
        const u32 pw3 = pack2(s[8*c+7], s[8*c+6]);
        const u32 px0 = (u32)__shfl_xor((int)pw0, 32, 64);
        const u32 px1 = (u32)__shfl_xor((int)pw1, 32, 64);
        const u32 px2 = (u32)__shfl_xor((int)pw2, 32, 64);
        const u32 px3 = (u32)__shfl_xor((int)pw3, 32, 64);
        int4v f;
        if (hi) { f.x=(int)px2; f.y=(int)px3; f.z=(int)pw2; f.w=(int)pw3; }
        else    { f.x=(int)pw0; f.y=(int)pw1; f.z=(int)px0; f.w=(int)px1; }
        *(int4v*)((char*)lds_P + ((2*w + c) * 64 + lane) * 16) = f;
      }
    }
    __syncthreads();                                   // BAR2: P ready

    // ---- PV: O^T[d-slice x 32q] += V^T * P^T, 64 loads, 8-deep V prefetch ----
    {
      const char* vt = vb + (size_t)kt * 16384;        // 16 kcg * 1024 B
      bf16x8 vbuf[8];
      #pragma unroll
      for (int i = 0; i < 8; ++i)
        vbuf[i] = *(const bf16x8*)(vt + (size_t)(i >> 2) * 1024 + (size_t)(i & 3) * 131072);
      __builtin_amdgcn_s_setprio(1);
      #pragma unroll
      for (int kcg = 0; kcg < 16; ++kcg) {
        const bf16x8 pb = *(const bf16x8*)((const char*)lds_P + (kcg * 64 + lane) * 16);
        #pragma unroll
        for (int nb = 0; nb < 4; ++nb) {
          const int j = kcg * 4 + nb;
          const bf16x8 vf = vbuf[j & 7];
          if (j < 56) {
            const int jn = j + 8;
            vbuf[j & 7] = *(const bf16x8*)(vt + (size_t)(jn >> 2) * 1024 + (size_t)(jn & 3) * 131072);
          }
          oacc[nb] = __builtin_amdgcn_mfma_f32_32x32x16_bf16(vf, pb, oacc[nb], 0, 0, 0);
        }
      }
      __builtin_amdgcn_s_setprio(0);
    }
  }

  // ---- epilogue: lane-32 exchange -> 16B q-major bf16 stores ----
  {
    unsigned short* obase = (h ? OB : OA) + ((size_t)(b * TB + q0 + lo5)) * DD + 128 * w;
    #pragma unroll
    for (int nb = 0; nb < 4; ++nb) {
      #pragma unroll
      for (int m2 = 0; m2 < 4; ++m2) {
        const u32 e0 = pack2(oacc[nb][4*m2+1], oacc[nb][4*m2+0]);
        const u32 e1 = pack2(oacc[nb][4*m2+3], oacc[nb][4*m2+2]);
        const u32 y0 = (u32)__shfl_xor((int)e0, 32, 64);
        const u32 y1 = (u32)__shfl_xor((int)e1, 32, 64);
        if (hi == (nb >> 1)) {
          int4v f;
          if (hi) { f.x=(int)y0; f.y=(int)y1; f.z=(int)e0; f.w=(int)e1; }
          else    { f.x=(int)e0; f.y=(int)e1; f.z=(int)y0; f.w=(int)y1; }
          *(int4v*)(obase + 32 * nb + 8 * m2) = f;
        }
      }
    }
  }
  if (lane < 32) lds_red[w][lo5] = l;
  __syncthreads();
  if (w == 0 && lane < 32) {
    float lt = 0.f;
    #pragma unroll
    for (int j = 0; j < 8; ++j) lt += lds_red[j][lo5];
    const int row = b * TB + q0 + lo5;
    ML[h * 16384 + row] = m;
    ML[h * 16384 + 8192 + row] = lt;
  }
}

// ===================== merge: O = (eA*OA~ + eB*OB~) / (eA*lA + eB*lB) ================
__global__ __launch_bounds__(256)
void merge_v4(float* __restrict__ O, const unsigned short* __restrict__ OA,
              const unsigned short* __restrict__ OB, const float* __restrict__ ML) {
  const int idx = blockIdx.x * 256 + threadIdx.x;   // 16 elems per thread
  const int row = idx >> 6;
  const float mAv = ML[row],         lAv = ML[8192 + row];
  const float mBv = ML[16384 + row], lBv = ML[24576 + row];
  const float m = fmaxf(mAv, mBv);
  const float eA = __expf(mAv - m), eB = __expf(mBv - m);
  const float inv = 1.0f / (eA * lAv + eB * lBv);
  const float fa = eA * inv, fb = eB * inv;
  const uint4* pa = (const uint4*)(OA + (size_t)idx * 16);
  const uint4* pb = (const uint4*)(OB + (size_t)idx * 16);
  float4* od = (float4*)(O + (size_t)idx * 16);
  #pragma unroll
  for (int g = 0; g < 2; ++g) {
    const uint4 ua = pa[g], ub = pb[g];
    const u32 wa[4] = {ua.x, ua.y, ua.z, ua.w};
    const u32 wb[4] = {ub.x, ub.y, ub.z, ub.w};
    float out[8];
    #pragma unroll
    for (int i = 0; i < 4; ++i) {
      const float aLo = __uint_as_float(wa[i] << 16);
      const float aHi = __uint_as_float(wa[i] & 0xffff0000u);
      const float bLo = __uint_as_float(wb[i] << 16);
      const float bHi = __uint_as_float(wb[i] & 0xffff0000u);
      out[2*i]   = fa * aLo + fb * bLo;
      out[2*i+1] = fa * aHi + fb * bHi;
    }
    od[2*g]   = make_float4(out[0], out[1], out[2], out[3]);
    od[2*g+1] = make_float4(out[4], out[5], out[6], out[7]);
  }
}

// ===================== fallback (v1, known good, no workspace) ======================
__global__ __launch_bounds__(512, 2)
void fa_fwd_f32_v1(const float* __restrict__ Q, const float* __restrict__ K,
                   const float* __restrict__ V, const int* __restrict__ AM,
                   float* __restrict__ O)
{
  __shared__ __align__(16) float lds_part[8][32 * 68];
  __shared__ __align__(16) unsigned short lds_Pf[32][72];
  __shared__ float lds_m[32], lds_l[32], lds_scale[32];
  __shared__ unsigned lds_mask32[TB / 4];
  __shared__ int lds_tv[32];

  const int tid  = threadIdx.x;
  const int w    = tid >> 6;
  const int lane = tid & 63;
  const int lo5  = lane & 31;
  const int hi   = lane >> 5;

  const int bid  = blockIdx.x;
  const int xcd  = bid & 7;
  const int slot = bid >> 3;
  const int b    = xcd >> 1;
  const int half = xcd & 1;
  const int qt   = half ? (16 + slot) : (slot < 16 ? slot : 32 + slot);
  const int q0   = qt << 5;

  const int4v mi = *(const int4v*)(AM + b * TB + 4 * tid);
  const unsigned mw = (mi.x ? 1u : 0u) | (mi.y ? 0x100u : 0u) |
                      (mi.z ? 0x10000u : 0u) | (mi.w ? 0x1000000u : 0u);
  lds_mask32[tid] = mw;
  if (tid < 32) { lds_tv[tid] = 0; lds_m[tid] = -1e30f; lds_l[tid] = 0.0f; }
  __syncthreads();
  if (mw) lds_tv[tid >> 4] = 1;

  bf16x8 qf[8];
  {
    const float* qrow = Q + ((size_t)b * TB + q0 + lo5) * DD + w * 128 + hi * 8;
    #pragma unroll
    for (int kk = 0; kk < 8; ++kk) {
      const float4 a = *(const float4*)(qrow + kk * 16);
      const float4 c = *(const float4*)(qrow + kk * 16 + 4);
      const float f[8] = {a.x * 0.03125f, a.y * 0.03125f, a.z * 0.03125f, a.w * 0.03125f,
                          c.x * 0.03125f, c.y * 0.03125f, c.z * 0.03125f, c.w * 0.03125f};
      qf[kk] = pack8(f);
    }
  }

  f32x16 oacc[4] = {f32x16{}, f32x16{}, f32x16{}, f32x16{}};
  const float* kbat = K + (size_t)b * TB * DD + w * 128 + hi * 8;
  const float* vbat = V + (size_t)b * TB * DD + w * 128;
  __syncthreads();

  const int nkt = (qt >> 1) + 1;
  for (int kt = 0; kt < nkt; ++kt) {
    if (!lds_tv[kt]) continue;
    const int k0 = kt << 6;
    f32x16 s0{}, s1{};
    const float* kb0 = kbat + (size_t)(k0 + lo5) * DD;
    #pragma unroll
    for (int kk = 0; kk < 8; ++kk) {
      const float4 a0 = *(const float4*)(kb0 + kk * 16);
      const float4 a1 = *(const float4*)(kb0 + kk * 16 + 4);
      const float f0[8] = {a0.x, a0.y, a0.z, a0.w, a1.x, a1.y, a1.z, a1.w};
      s0 = __builtin_amdgcn_mfma_f32_32x32x16_bf16(qf[kk], pack8(f0), s0, 0, 0, 0);
      const float4 c0 = *(const float4*)(kb0 + (size_t)32 * DD + kk * 16);
      const float4 c1 = *(const float4*)(kb0 + (size_t)32 * DD + kk * 16 + 4);
      const float f1[8] = {c0.x, c0.y, c0.z, c0.w, c1.x, c1.y, c1.z, c1.w};
      s1 = __builtin_amdgcn_mfma_f32_32x32x16_bf16(qf[kk], pack8(f1), s1, 0, 0, 0);
    }
    {
      float* wp = lds_part[w];
      const int pos = lo5 + (hi << 5);
      #pragma unroll
      for (int r = 0; r < 16; ++r) {
        wp[r * 68 + pos]        = s0[r];
        wp[(16 + r) * 68 + pos] = s1[r];
      }
    }
    __syncthreads();
    {
      const int r = tid >> 4, g = tid & 15;
      const int regp  = (r & 3) | (((r >> 3) & 3) << 2);
      const int plane = ((g >> 3) << 4) + regp;
      const int pos   = ((4 * g) & 31) + (((r >> 2) & 1) << 5);
      float s[4] = {0.f, 0.f, 0.f, 0.f};
      #pragma unroll
      for (int ww = 0; ww < 8; ++ww) {
        const float4 v4 = *(const float4*)&lds_part[ww][plane * 68 + pos];
        s[0] += v4.x; s[1] += v4.y; s[2] += v4.z; s[3] += v4.w;
      }
      const unsigned mv = lds_mask32[(k0 >> 2) + g];
      const int qq = q0 + r;
      #pragma unroll
      for (int i = 0; i < 4; ++i) {
        const int kg = k0 + 4 * g + i;
        const bool ok = (((mv >> (8 * i)) & 0xffu) != 0u) && (kg <= qq);
        if (!ok) s[i] = -1e30f;
      }
      float mx = fmaxf(fmaxf(s[0], s[1]), fmaxf(s[2], s[3]));
      #pragma unroll
      for (int d = 1; d < 16; d <<= 1) mx = fmaxf(mx, __shfl_xor(mx, d, 64));
      const float mold = lds_m[r];
      const float mnew = fmaxf(mold, mx);
      float p[4], lsv = 0.f;
      #pragma unroll
      for (int i = 0; i < 4; ++i) { p[i] = __expf(s[i] - mnew); lsv += p[i]; }
      #pragma unroll
      for (int d = 1; d < 16; d <<= 1) lsv += __shfl_xor(lsv, d, 64);
      const float resc = __expf(mold - mnew);
      if (g == 0) {
        lds_m[r]     = mnew;
        lds_l[r]     = lds_l[r] * resc + lsv;
        lds_scale[r] = resc;
      }
      unsigned* pp = (unsigned*)&lds_Pf[r][4 * g];
      pp[0] = pack2(p[1], p[0]);
      pp[1] = pack2(p[3], p[2]);
    }
    __syncthreads();
    {
      float scv[16];
      #pragma unroll
      for (int reg = 0; reg < 16; ++reg)
        scv[reg] = lds_scale[(reg & 3) + ((reg >> 2) << 3) + (hi << 2)];
      #pragma unroll
      for (int nb = 0; nb < 4; ++nb) {
        #pragma unroll
        for (int reg = 0; reg < 16; ++reg) oacc[nb][reg] *= scv[reg];
      }
      bf16x8 pf[4];
      #pragma unroll
      for (int kc = 0; kc < 4; ++kc)
        pf[kc] = __builtin_bit_cast(bf16x8, *(const int4v*)&lds_Pf[lo5][kc * 16 + hi * 8]);
      const float* vbp = vbat + (size_t)k0 * DD + lo5;
      #pragma unroll
      for (int kc = 0; kc < 4; ++kc) {
        const float* vr = vbp + (size_t)(kc * 16 + hi * 8) * DD;
        float fv[4][8];
        #pragma unroll
        for (int j = 0; j < 8; ++j) {
          const float* vrj = vr + (size_t)j * DD;
          #pragma unroll
          for (int nb = 0; nb < 4; ++nb) fv[nb][j] = vrj[nb * 32];
        }
        #pragma unroll
        for (int nb = 0; nb < 4; ++nb)
          oacc[nb] = __builtin_amdgcn_mfma_f32_32x32x16_bf16(pf[kc], pack8(fv[nb]), oacc[nb], 0, 0, 0);
      }
    }
    __syncthreads();
  }

  float il[16];
  #pragma unroll
  for (int reg = 0; reg < 16; ++reg)
    il[reg] = 1.0f / lds_l[(reg & 3) + ((reg >> 2) << 3) + (hi << 2)];
  float* ob = O + ((size_t)b * TB + q0) * DD + w * 128;
  #pragma unroll
  for (int nb = 0; nb < 4; ++nb) {
    #pragma unroll
    for (int reg = 0; reg < 16; ++reg) {
      const int row = (reg & 3) + ((reg >> 2) << 3) + (hi << 2);
      ob[(size_t)row * DD + nb * 32 + lo5] = oacc[nb][reg] * il[reg];
    }
  }
}

extern "C" void kernel_launch(void* const* d_in, const int* in_sizes, int n_in,
                              void* d_out, int out_size, void* d_ws, size_t ws_size,
                              hipStream_t stream) {
  const float* Q  = (const float*)d_in[0];
  const float* K  = (const float*)d_in[1];
  const float* V  = (const float*)d_in[2];
  const int*   AM = (const int*)d_in[3];
  float* O = (float*)d_out;
  (void)in_sizes; (void)n_in; (void)out_size;

  const size_t SZ = 16777216;                 // each of Kf/Vf/Qf/OA/OB
  const size_t need = 5 * SZ + 131072;        // + ML
  if (ws_size >= need) {
    unsigned short* Kf = (unsigned short*)d_ws;
    unsigned short* Vf = (unsigned short*)((char*)d_ws + SZ);
    unsigned short* Qf = (unsigned short*)((char*)d_ws + 2 * SZ);
    unsigned short* OA = (unsigned short*)((char*)d_ws + 3 * SZ);
    unsigned short* OB = (unsigned short*)((char*)d_ws + 4 * SZ);
    float*          ML = (float*)((char*)d_ws + 5 * SZ);
    hipLaunchKernelGGL(conv_all, dim3(1024), dim3(256), 0, stream, Q, K, V, Qf, Kf, Vf);
    hipLaunchKernelGGL(fa_fwd_f32_v8, dim3(512), dim3(512), 0, stream,
                       Qf, AM, Kf, Vf, OA, OB, ML);
    hipLaunchKernelGGL(merge_v4, dim3(2048), dim3(256), 0, stream, O, OA, OB, ML);
  } else {
    hipLaunchKernelGGL(fa_fwd_f32_v1, dim3(256), dim3(512), 0, stream, Q, K, V, AM, O);
  }
}

// Round 10
// 117.686 us; speedup vs baseline: 1.2471x; 1.2471x over previous
//
#include <hip/hip_runtime.h>
#include <stdint.h>

// SelfAttention: B=4, T=2048, EMB=1024, causal + key padding (last 256 keys)
#define TB 2048
#define DD 1024

typedef __bf16 bf16x8 __attribute__((ext_vector_type(8)));
typedef float  f32x16 __attribute__((ext_vector_type(16)));
typedef int    int4v  __attribute__((ext_vector_type(4)));
typedef unsigned u32;

__device__ __forceinline__ u32 pack2(float hi, float lo) {
  return (__float_as_uint(hi) & 0xffff0000u) | (__float_as_uint(lo) >> 16);
}
__device__ __forceinline__ bf16x8 pack8(const float f[8]) {
  int4v w;
  w.x = (int)pack2(f[1], f[0]);
  w.y = (int)pack2(f[3], f[2]);
  w.z = (int)pack2(f[5], f[4]);
  w.w = (int)pack2(f[7], f[6]);
  return __builtin_bit_cast(bf16x8, w);
}

// ===================== fused pre-pass: Q,K,V -> bf16 fragments =====================
__global__ __launch_bounds__(256)
void conv_all(const float* __restrict__ Q, const float* __restrict__ K,
              const float* __restrict__ V,
              unsigned short* __restrict__ Qf, unsigned short* __restrict__ Kf,
              unsigned short* __restrict__ Vf) {
  __shared__ __align__(16) float t[64 * 260];
  if (blockIdx.x < 512) {
    const int isQ = blockIdx.x >> 8;
    const int bid = blockIdx.x & 255;
    const float* src0 = isQ ? Q : K;
    unsigned short* dst0 = isQ ? Qf : Kf;
    const float scl = isQ ? 0.03125f : 1.0f;
    const int b  = bid >> 6;
    const int kt = bid & 63;
    const int lt  = threadIdx.x & 63;
    const int row = lt & 31, hi = lt >> 5;
    const int wv  = threadIdx.x >> 6;
    const float* src = src0 + ((size_t)(b * TB + kt * 32 + row)) * DD + hi * 8;
    unsigned short* dst = dst0 + ((size_t)(b * 64 + kt) * 64) * 512 + lt * 8;
    #pragma unroll
    for (int i = 0; i < 16; ++i) {
      const int ds = wv + 4 * i;
      const float4 a = *(const float4*)(src + ds * 16);
      const float4 c = *(const float4*)(src + ds * 16 + 4);
      const float f[8] = {a.x*scl, a.y*scl, a.z*scl, a.w*scl,
                          c.x*scl, c.y*scl, c.z*scl, c.w*scl};
      *(int4v*)(dst + (size_t)ds * 512) = __builtin_bit_cast(int4v, pack8(f));
    }
  } else {
    const int bid = blockIdx.x - 512;
    const int b   = bid >> 7;
    const int kb  = (bid >> 2) & 31;
    const int db  = bid & 3;
    const int k0 = kb * 64, d0 = db * 256;
    {
      const int f = threadIdx.x & 63;
      const int r0 = threadIdx.x >> 6;
      #pragma unroll
      for (int i = 0; i < 16; ++i) {
        const int kloc = r0 + 4 * i;
        const float4 v4 = *(const float4*)(V + ((size_t)(b * TB + k0 + kloc)) * DD + d0 + f * 4);
        *(float4*)(t + kloc * 260 + f * 4) = v4;
      }
    }
    __syncthreads();
    const int lt  = threadIdx.x & 63;
    const int lo5 = lt & 31, hi = lt >> 5;
    const int kk  = threadIdx.x >> 6;
    #pragma unroll
    for (int dd = 0; dd < 8; ++dd) {
      float f[8];
      #pragma unroll
      for (int j = 0; j < 8; ++j)
        f[j] = t[(kk * 16 + hi * 8 + j) * 260 + dd * 32 + lo5];
      unsigned short* dst = Vf +
          (((size_t)(b * 32 + (d0 >> 5) + dd) * 128 + (k0 >> 4) + kk) * 64 + lt) * 8;
      *(int4v*)dst = __builtin_bit_cast(int4v, pack8(f));
    }
  }
}

// Non-draining barrier: LDS visibility only, keeps VMEM loads in flight.
__device__ __forceinline__ void lds_barrier() {
  __builtin_amdgcn_sched_barrier(0);
  asm volatile("s_waitcnt lgkmcnt(0)");
  __builtin_amdgcn_s_barrier();
  __builtin_amdgcn_sched_barrier(0);
}

// ===================== main kernel v9: v6 + asm 16-deep counted-vmcnt pipelines =====
// Grid 512: block = (b, qt 0..63, key-half h), heaviest qt dispatched first.
// QK: wave w owns keys [k0+32w, +32), full d; Q from LDS, K streamed (asm pf).
// PV: wave w owns d slice [128w, +128); P single-phase 16KB LDS; V asm pf,
//     issued BEFORE softmax so latency hides under it (barriers don't drain vmcnt).
__global__ __launch_bounds__(512, 2)
void fa_fwd_f32_v9(const unsigned short* __restrict__ Qf, const int* __restrict__ AM,
                   const unsigned short* __restrict__ Kf, const unsigned short* __restrict__ Vf,
                   unsigned short* __restrict__ OA, unsigned short* __restrict__ OB,
                   float* __restrict__ ML)
{
  __shared__ __align__(16) unsigned short lds_Q[64 * 64 * 8];   // 65536 B [ds][lane][8]
  __shared__ __align__(16) unsigned short lds_P[16 * 64 * 8];   // 16384 B [kc][lane][8]
  __shared__ float lds_red[8][32];                              // 1024 B
  __shared__ unsigned char lds_nib[512];                        // pad-mask nibbles
  __shared__ int lds_tvi;

  const int tid  = threadIdx.x;
  const int w    = tid >> 6;
  const int lane = tid & 63;
  const int lo5  = lane & 31;
  const int hi   = lane >> 5;

  const int bid  = blockIdx.x;
  const int xcd  = bid & 7, slot = bid >> 3;       // slot 0..63
  const int b    = xcd >> 1, x = xcd & 1;
  const int rank = slot >> 1, h = slot & 1;
  const int qt   = 63 - 2 * rank - x;              // heavy-first LPT
  const int q0   = qt << 5;

  // ---- stage Q tile (frag order, contiguous) + pad-mask nibbles ----
  {
    const char* qsrc = (const char*)Qf + ((size_t)(b * 64 + qt)) * 65536 + tid * 16;
    #pragma unroll
    for (int i = 0; i < 8; ++i)
      *(int4v*)((char*)lds_Q + tid * 16 + i * 8192) = *(const int4v*)(qsrc + (size_t)i * 8192);
  }
  if (tid == 0) lds_tvi = 0;
  __syncthreads();
  {
    const int4v mi = *(const int4v*)(AM + b * TB + 4 * tid);
    const unsigned char nib = (mi.x?1:0)|(mi.y?2:0)|(mi.z?4:0)|(mi.w?8:0);
    lds_nib[tid] = nib;
    if (nib) atomicOr(&lds_tvi, 1 << (tid >> 6));
  }
  __syncthreads();
  const int tvbits = lds_tvi;

  float m = -1e30f, l = 0.f;
  f32x16 oacc[4] = {f32x16{}, f32x16{}, f32x16{}, f32x16{}};

  const char* vb = (const char*)Vf + ((size_t)(b * 32 + 4 * w)) * 131072 + lane * 16;
  const int q = q0 + lo5;
  const int diag_kt = qt >> 3;

  const int nkt = diag_kt + 1;
  for (int kt = h; kt < nkt; kt += 2) {
    if (!(tvbits & (1 << kt))) continue;
    const int k0 = kt << 8;

    // ---- QK^T swapped, 16-deep asm K pipeline (counted vmcnt, never drained) ----
    f32x16 s0{}, s1{};
    {
      const char* kp = (const char*)Kf + ((size_t)(b * 64 + kt * 8 + w)) * 65536 + lane * 16;
      const char* qp = (const char*)lds_Q + lane * 16;
      int4v kb[16];
      #pragma unroll
      for (int i = 0; i < 16; ++i)
        asm volatile("global_load_dwordx4 %0, %1, off"
                     : "=v"(kb[i]) : "v"(kp + (size_t)i * 1024));
      __builtin_amdgcn_s_setprio(1);
      #pragma unroll
      for (int g = 0; g < 8; ++g) {
        if (g < 7) asm volatile("s_waitcnt vmcnt(8)");
        else       asm volatile("s_waitcnt vmcnt(0)");
        __builtin_amdgcn_sched_barrier(0);
        #pragma unroll
        for (int j = 0; j < 8; j += 2) {
          const int ds = 8 * g + j;
          s0 = __builtin_amdgcn_mfma_f32_32x32x16_bf16(
              __builtin_bit_cast(bf16x8, kb[ds & 15]),
              *(const bf16x8*)(qp + (size_t)ds * 1024), s0, 0, 0, 0);
          s1 = __builtin_amdgcn_mfma_f32_32x32x16_bf16(
              __builtin_bit_cast(bf16x8, kb[(ds + 1) & 15]),
              *(const bf16x8*)(qp + (size_t)(ds + 1) * 1024), s1, 0, 0, 0);
        }
        if (g < 6) {
          #pragma unroll
          for (int j = 0; j < 8; ++j) {
            const int dsn = 8 * (g + 2) + j;
            asm volatile("global_load_dwordx4 %0, %1, off"
                         : "=v"(kb[dsn & 15]) : "v"(kp + (size_t)dsn * 1024));
          }
        }
      }
      __builtin_amdgcn_s_setprio(0);
    }

    // ---- issue V prologue NOW: latency hides under softmax + barriers ----
    int4v vbv[16];
    {
      const char* vt = vb + (size_t)kt * 16384;
      #pragma unroll
      for (int i = 0; i < 16; ++i)
        asm volatile("global_load_dwordx4 %0, %1, off"
                     : "=v"(vbv[i])
                     : "v"(vt + (size_t)(i >> 2) * 1024 + (size_t)(i & 3) * 131072));
    }

    // ---- merge chains, mask (fast path off-diagonal), wave max ----
    u32 mw;
    {
      const u32* nw = (const u32*)(lds_nib + 64 * kt + 8 * w);
      const u32 n0 = nw[0], n1 = nw[1];
      mw = (n0 & 0xFu) | ((n0 >> 4) & 0xF0u) | ((n0 >> 8) & 0xF00u) | ((n0 >> 12) & 0xF000u);
      mw |= ((n1 & 0xFu) | ((n1 >> 4) & 0xF0u) | ((n1 >> 8) & 0xF00u) | ((n1 >> 12) & 0xF000u)) << 16;
    }
    float s[16];
    float mx = -1e30f;
    if (kt != diag_kt && mw == 0xffffffffu) {
      #pragma unroll
      for (int r = 0; r < 16; ++r) { s[r] = s0[r] + s1[r]; mx = fmaxf(mx, s[r]); }
    } else {
      #pragma unroll
      for (int r = 0; r < 16; ++r) {
        const int kl = (r & 3) + 8 * (r >> 2) + 4 * hi;
        const bool ok = (((mw >> kl) & 1u) != 0u) && (k0 + 32 * w + kl <= q);
        s[r] = ok ? (s0[r] + s1[r]) : -1e30f;
        mx = fmaxf(mx, s[r]);
      }
    }
    mx = fmaxf(mx, __shfl_xor(mx, 32, 64));
    if (lane < 32) lds_red[w][lo5] = mx;
    lds_barrier();                                     // BAR1 (no vmcnt drain)

    float gm = m;
    #pragma unroll
    for (int j = 0; j < 8; ++j) gm = fmaxf(gm, lds_red[j][lo5]);
    const float sc = __expf(m - gm);
    m = gm;
    const float pm = fmaxf(gm, -1e28f);                // all-masked guard
    float ls = 0.f;
    #pragma unroll
    for (int r = 0; r < 16; ++r) { s[r] = __expf(s[r] - pm); ls += s[r]; }
    ls += __shfl_xor(ls, 32, 64);
    l = l * sc + ls;
    #pragma unroll
    for (int nb = 0; nb < 4; ++nb)
      #pragma unroll
      for (int r = 0; r < 16; ++r) oacc[nb][r] *= sc;

    // P^T frag write: wave w owns kc slots 2w, 2w+1
    {
      #pragma unroll
      for (int c = 0; c < 2; ++c) {
        const u32 pw0 = pack2(s[8*c+1], s[8*c+0]);
        const u32 pw1 = pack2(s[8*c+3], s[8*c+2]);
        const u32 pw2 = pack2(s[8*c+5], s[8*c+4]);
        const u32 pw3 = pack2(s[8*c+7], s[8*c+6]);
        const u32 px0 = (u32)__shfl_xor((int)pw0, 32, 64);
        const u32 px1 = (u32)__shfl_xor((int)pw1, 32, 64);
        const u32 px2 = (u32)__shfl_xor((int)pw2, 32, 64);
        const u32 px3 = (u32)__shfl_xor((int)pw3, 32, 64);
        int4v f;
        if (hi) { f.x=(int)px2; f.y=(int)px3; f.z=(int)pw2; f.w=(int)pw3; }
        else    { f.x=(int)pw0; f.y=(int)pw1; f.z=(int)px0; f.w=(int)px1; }
        *(int4v*)((char*)lds_P + ((2*w + c) * 64 + lane) * 16) = f;
      }
    }
    lds_barrier();                                     // BAR2 (no vmcnt drain)

    // ---- PV: 16-deep asm V pipeline (prologue already in flight) ----
    {
      const char* vt = vb + (size_t)kt * 16384;
      __builtin_amdgcn_s_setprio(1);
      #pragma unroll
      for (int g = 0; g < 8; ++g) {
        if (g < 7) asm volatile("s_waitcnt vmcnt(8)");
        else       asm volatile("s_waitcnt vmcnt(0)");
        __builtin_amdgcn_sched_barrier(0);
        #pragma unroll
        for (int kk = 0; kk < 2; ++kk) {
          const int kcg = 2 * g + kk;
          const bf16x8 pb = *(const bf16x8*)((const char*)lds_P + (kcg * 64 + lane) * 16);
          #pragma unroll
          for (int nb = 0; nb < 4; ++nb) {
            const int idx = kcg * 4 + nb;
            oacc[nb] = __builtin_amdgcn_mfma_f32_32x32x16_bf16(
                __builtin_bit_cast(bf16x8, vbv[idx & 15]), pb, oacc[nb], 0, 0, 0);
          }
        }
        if (g < 6) {
          #pragma unroll
          for (int j = 0; j < 8; ++j) {
            const int idxn = 8 * (g + 2) + j;
            asm volatile("global_load_dwordx4 %0, %1, off"
                         : "=v"(vbv[idxn & 15])
                         : "v"(vt + (size_t)(idxn >> 2) * 1024 + (size_t)(idxn & 3) * 131072));
          }
        }
      }
      __builtin_amdgcn_s_setprio(0);
    }
  }

  // ---- epilogue: lane-32 exchange -> 16B q-major bf16 stores ----
  {
    unsigned short* obase = (h ? OB : OA) + ((size_t)(b * TB + q0 + lo5)) * DD + 128 * w;
    #pragma unroll
    for (int nb = 0; nb < 4; ++nb) {
      #pragma unroll
      for (int m2 = 0; m2 < 4; ++m2) {
        const u32 e0 = pack2(oacc[nb][4*m2+1], oacc[nb][4*m2+0]);
        const u32 e1 = pack2(oacc[nb][4*m2+3], oacc[nb][4*m2+2]);
        const u32 y0 = (u32)__shfl_xor((int)e0, 32, 64);
        const u32 y1 = (u32)__shfl_xor((int)e1, 32, 64);
        if (hi == (nb >> 1)) {
          int4v f;
          if (hi) { f.x=(int)y0; f.y=(int)y1; f.z=(int)e0; f.w=(int)e1; }
          else    { f.x=(int)e0; f.y=(int)e1; f.z=(int)y0; f.w=(int)y1; }
          *(int4v*)(obase + 32 * nb + 8 * m2) = f;
        }
      }
    }
  }
  if (lane < 32) lds_red[w][lo5] = l;
  __syncthreads();
  if (w == 0 && lane < 32) {
    float lt = 0.f;
    #pragma unroll
    for (int j = 0; j < 8; ++j) lt += lds_red[j][lo5];
    const int row = b * TB + q0 + lo5;
    ML[h * 16384 + row] = m;
    ML[h * 16384 + 8192 + row] = lt;
  }
}

// ===================== merge: O = (eA*OA~ + eB*OB~) / (eA*lA + eB*lB) ================
__global__ __launch_bounds__(256)
void merge_v4(float* __restrict__ O, const unsigned short* __restrict__ OA,
              const unsigned short* __restrict__ OB, const float* __restrict__ ML) {
  const int idx = blockIdx.x * 256 + threadIdx.x;   // 16 elems per thread
  const int row = idx >> 6;
  const float mAv = ML[row],         lAv = ML[8192 + row];
  const float mBv = ML[16384 + row], lBv = ML[24576 + row];
  const float m = fmaxf(mAv, mBv);
  const float eA = __expf(mAv - m), eB = __expf(mBv - m);
  const float inv = 1.0f / (eA * lAv + eB * lBv);
  const float fa = eA * inv, fb = eB * inv;
  const uint4* pa = (const uint4*)(OA + (size_t)idx * 16);
  const uint4* pb = (const uint4*)(OB + (size_t)idx * 16);
  float4* od = (float4*)(O + (size_t)idx * 16);
  #pragma unroll
  for (int g = 0; g < 2; ++g) {
    const uint4 ua = pa[g], ub = pb[g];
    const u32 wa[4] = {ua.x, ua.y, ua.z, ua.w};
    const u32 wb[4] = {ub.x, ub.y, ub.z, ub.w};
    float out[8];
    #pragma unroll
    for (int i = 0; i < 4; ++i) {
      const float aLo = __uint_as_float(wa[i] << 16);
      const float aHi = __uint_as_float(wa[i] & 0xffff0000u);
      const float bLo = __uint_as_float(wb[i] << 16);
      const float bHi = __uint_as_float(wb[i] & 0xffff0000u);
      out[2*i]   = fa * aLo + fb * bLo;
      out[2*i+1] = fa * aHi + fb * bHi;
    }
    od[2*g]   = make_float4(out[0], out[1], out[2], out[3]);
    od[2*g+1] = make_float4(out[4], out[5], out[6], out[7]);
  }
}

// ===================== fallback (v1, known good, no workspace) ======================
__global__ __launch_bounds__(512, 2)
void fa_fwd_f32_v1(const float* __restrict__ Q, const float* __restrict__ K,
                   const float* __restrict__ V, const int* __restrict__ AM,
                   float* __restrict__ O)
{
  __shared__ __align__(16) float lds_part[8][32 * 68];
  __shared__ __align__(16) unsigned short lds_Pf[32][72];
  __shared__ float lds_m[32], lds_l[32], lds_scale[32];
  __shared__ unsigned lds_mask32[TB / 4];
  __shared__ int lds_tv[32];

  const int tid  = threadIdx.x;
  const int w    = tid >> 6;
  const int lane = tid & 63;
  const int lo5  = lane & 31;
  const int hi   = lane >> 5;

  const int bid  = blockIdx.x;
  const int xcd  = bid & 7;
  const int slot = bid >> 3;
  const int b    = xcd >> 1;
  const int half = xcd & 1;
  const int qt   = half ? (16 + slot) : (slot < 16 ? slot : 32 + slot);
  const int q0   = qt << 5;

  const int4v mi = *(const int4v*)(AM + b * TB + 4 * tid);
  const unsigned mw = (mi.x ? 1u : 0u) | (mi.y ? 0x100u : 0u) |
                      (mi.z ? 0x10000u : 0u) | (mi.w ? 0x1000000u : 0u);
  lds_mask32[tid] = mw;
  if (tid < 32) { lds_tv[tid] = 0; lds_m[tid] = -1e30f; lds_l[tid] = 0.0f; }
  __syncthreads();
  if (mw) lds_tv[tid >> 4] = 1;

  bf16x8 qf[8];
  {
    const float* qrow = Q + ((size_t)b * TB + q0 + lo5) * DD + w * 128 + hi * 8;
    #pragma unroll
    for (int kk = 0; kk < 8; ++kk) {
      const float4 a = *(const float4*)(qrow + kk * 16);
      const float4 c = *(const float4*)(qrow + kk * 16 + 4);
      const float f[8] = {a.x * 0.03125f, a.y * 0.03125f, a.z * 0.03125f, a.w * 0.03125f,
                          c.x * 0.03125f, c.y * 0.03125f, c.z * 0.03125f, c.w * 0.03125f};
      qf[kk] = pack8(f);
    }
  }

  f32x16 oacc[4] = {f32x16{}, f32x16{}, f32x16{}, f32x16{}};
  const float* kbat = K + (size_t)b * TB * DD + w * 128 + hi * 8;
  const float* vbat = V + (size_t)b * TB * DD + w * 128;
  __syncthreads();

  const int nkt = (qt >> 1) + 1;
  for (int kt = 0; kt < nkt; ++kt) {
    if (!lds_tv[kt]) continue;
    const int k0 = kt << 6;
    f32x16 s0{}, s1{};
    const float* kb0 = kbat + (size_t)(k0 + lo5) * DD;
    #pragma unroll
    for (int kk = 0; kk < 8; ++kk) {
      const float4 a0 = *(const float4*)(kb0 + kk * 16);
      const float4 a1 = *(const float4*)(kb0 + kk * 16 + 4);
      const float f0[8] = {a0.x, a0.y, a0.z, a0.w, a1.x, a1.y, a1.z, a1.w};
      s0 = __builtin_amdgcn_mfma_f32_32x32x16_bf16(qf[kk], pack8(f0), s0, 0, 0, 0);
      const float4 c0 = *(const float4*)(kb0 + (size_t)32 * DD + kk * 16);
      const float4 c1 = *(const float4*)(kb0 + (size_t)32 * DD + kk * 16 + 4);
      const float f1[8] = {c0.x, c0.y, c0.z, c0.w, c1.x, c1.y, c1.z, c1.w};
      s1 = __builtin_amdgcn_mfma_f32_32x32x16_bf16(qf[kk], pack8(f1), s1, 0, 0, 0);
    }
    {
      float* wp = lds_part[w];
      const int pos = lo5 + (hi << 5);
      #pragma unroll
      for (int r = 0; r < 16; ++r) {
        wp[r * 68 + pos]        = s0[r];
        wp[(16 + r) * 68 + pos] = s1[r];
      }
    }
    __syncthreads();
    {
      const int r = tid >> 4, g = tid & 15;
      const int regp  = (r & 3) | (((r >> 3) & 3) << 2);
      const int plane = ((g >> 3) << 4) + regp;
      const int pos   = ((4 * g) & 31) + (((r >> 2) & 1) << 5);
      float s[4] = {0.f, 0.f, 0.f, 0.f};
      #pragma unroll
      for (int ww = 0; ww < 8; ++ww) {
        const float4 v4 = *(const float4*)&lds_part[ww][plane * 68 + pos];
        s[0] += v4.x; s[1] += v4.y; s[2] += v4.z; s[3] += v4.w;
      }
      const unsigned mv = lds_mask32[(k0 >> 2) + g];
      const int qq = q0 + r;
      #pragma unroll
      for (int i = 0; i < 4; ++i) {
        const int kg = k0 + 4 * g + i;
        const bool ok = (((mv >> (8 * i)) & 0xffu) != 0u) && (kg <= qq);
        if (!ok) s[i] = -1e30f;
      }
      float mx = fmaxf(fmaxf(s[0], s[1]), fmaxf(s[2], s[3]));
      #pragma unroll
      for (int d = 1; d < 16; d <<= 1) mx = fmaxf(mx, __shfl_xor(mx, d, 64));
      const float mold = lds_m[r];
      const float mnew = fmaxf(mold, mx);
      float p[4], lsv = 0.f;
      #pragma unroll
      for (int i = 0; i < 4; ++i) { p[i] = __expf(s[i] - mnew); lsv += p[i]; }
      #pragma unroll
      for (int d = 1; d < 16; d <<= 1) lsv += __shfl_xor(lsv, d, 64);
      const float resc = __expf(mold - mnew);
      if (g == 0) {
        lds_m[r]     = mnew;
        lds_l[r]     = lds_l[r] * resc + lsv;
        lds_scale[r] = resc;
      }
      unsigned* pp = (unsigned*)&lds_Pf[r][4 * g];
      pp[0] = pack2(p[1], p[0]);
      pp[1] = pack2(p[3], p[2]);
    }
    __syncthreads();
    {
      float scv[16];
      #pragma unroll
      for (int reg = 0; reg < 16; ++reg)
        scv[reg] = lds_scale[(reg & 3) + ((reg >> 2) << 3) + (hi << 2)];
      #pragma unroll
      for (int nb = 0; nb < 4; ++nb) {
        #pragma unroll
        for (int reg = 0; reg < 16; ++reg) oacc[nb][reg] *= scv[reg];
      }
      bf16x8 pf[4];
      #pragma unroll
      for (int kc = 0; kc < 4; ++kc)
        pf[kc] = __builtin_bit_cast(bf16x8, *(const int4v*)&lds_Pf[lo5][kc * 16 + hi * 8]);
      const float* vbp = vbat + (size_t)k0 * DD + lo5;
      #pragma unroll
      for (int kc = 0; kc < 4; ++kc) {
        const float* vr = vbp + (size_t)(kc * 16 + hi * 8) * DD;
        float fv[4][8];
        #pragma unroll
        for (int j = 0; j < 8; ++j) {
          const float* vrj = vr + (size_t)j * DD;
          #pragma unroll
          for (int nb = 0; nb < 4; ++nb) fv[nb][j] = vrj[nb * 32];
        }
        #pragma unroll
        for (int nb = 0; nb < 4; ++nb)
          oacc[nb] = __builtin_amdgcn_mfma_f32_32x32x16_bf16(pf[kc], pack8(fv[nb]), oacc[nb], 0, 0, 0);
      }
    }
    __syncthreads();
  }

  float il[16];
  #pragma unroll
  for (int reg = 0; reg < 16; ++reg)
    il[reg] = 1.0f / lds_l[(reg & 3) + ((reg >> 2) << 3) + (hi << 2)];
  float* ob = O + ((size_t)b * TB + q0) * DD + w * 128;
  #pragma unroll
  for (int nb = 0; nb < 4; ++nb) {
    #pragma unroll
    for (int reg = 0; reg < 16; ++reg) {
      const int row = (reg & 3) + ((reg >> 2) << 3) + (hi << 2);
      ob[(size_t)row * DD + nb * 32 + lo5] = oacc[nb][reg] * il[reg];
    }
  }
}

extern "C" void kernel_launch(void* const* d_in, const int* in_sizes, int n_in,
                              void* d_out, int out_size, void* d_ws, size_t ws_size,
                              hipStream_t stream) {
  const float* Q  = (const float*)d_in[0];
  const float* K  = (const float*)d_in[1];
  const float* V  = (const float*)d_in[2];
  const int*   AM = (const int*)d_in[3];
  float* O = (float*)d_out;
  (void)in_sizes; (void)n_in; (void)out_size;

  const size_t SZ = 16777216;                 // each of Kf/Vf/Qf/OA/OB
  const size_t need = 5 * SZ + 131072;        // + ML
  if (ws_size >= need) {
    unsigned short* Kf = (unsigned short*)d_ws;
    unsigned short* Vf = (unsigned short*)((char*)d_ws + SZ);
    unsigned short* Qf = (unsigned short*)((char*)d_ws + 2 * SZ);
    unsigned short* OA = (unsigned short*)((char*)d_ws + 3 * SZ);
    unsigned short* OB = (unsigned short*)((char*)d_ws + 4 * SZ);
    float*          ML = (float*)((char*)d_ws + 5 * SZ);
    hipLaunchKernelGGL(conv_all, dim3(1024), dim3(256), 0, stream, Q, K, V, Qf, Kf, Vf);
    hipLaunchKernelGGL(fa_fwd_f32_v9, dim3(512), dim3(512), 0, stream,
                       Qf, AM, Kf, Vf, OA, OB, ML);
    hipLaunchKernelGGL(merge_v4, dim3(2048), dim3(256), 0, stream, O, OA, OB, ML);
  } else {
    hipLaunchKernelGGL(fa_fwd_f32_v1, dim3(256), dim3(512), 0, stream, Q, K, V, AM, O);
  }
}

// Round 11
// 117.137 us; speedup vs baseline: 1.2530x; 1.0047x over previous
//
#include <hip/hip_runtime.h>
#include <stdint.h>

// SelfAttention: B=4, T=2048, EMB=1024, causal + key padding (last 256 keys)
#define TB 2048
#define DD 1024

typedef __bf16 bf16x8 __attribute__((ext_vector_type(8)));
typedef float  f32x16 __attribute__((ext_vector_type(16)));
typedef int    int4v  __attribute__((ext_vector_type(4)));
typedef unsigned u32;

__device__ __forceinline__ u32 pack2(float hi, float lo) {
  return (__float_as_uint(hi) & 0xffff0000u) | (__float_as_uint(lo) >> 16);
}
__device__ __forceinline__ bf16x8 pack8(const float f[8]) {
  int4v w;
  w.x = (int)pack2(f[1], f[0]);
  w.y = (int)pack2(f[3], f[2]);
  w.z = (int)pack2(f[5], f[4]);
  w.w = (int)pack2(f[7], f[6]);
  return __builtin_bit_cast(bf16x8, w);
}

// ===================== fused pre-pass: Q,K,V -> bf16 fragments =====================
__global__ __launch_bounds__(256)
void conv_all(const float* __restrict__ Q, const float* __restrict__ K,
              const float* __restrict__ V,
              unsigned short* __restrict__ Qf, unsigned short* __restrict__ Kf,
              unsigned short* __restrict__ Vf) {
  __shared__ __align__(16) float t[64 * 260];
  if (blockIdx.x < 512) {
    const int isQ = blockIdx.x >> 8;
    const int bid = blockIdx.x & 255;
    const float* src0 = isQ ? Q : K;
    unsigned short* dst0 = isQ ? Qf : Kf;
    const float scl = isQ ? 0.03125f : 1.0f;
    const int b  = bid >> 6;
    const int kt = bid & 63;
    const int lt  = threadIdx.x & 63;
    const int row = lt & 31, hi = lt >> 5;
    const int wv  = threadIdx.x >> 6;
    const float* src = src0 + ((size_t)(b * TB + kt * 32 + row)) * DD + hi * 8;
    unsigned short* dst = dst0 + ((size_t)(b * 64 + kt) * 64) * 512 + lt * 8;
    #pragma unroll
    for (int i = 0; i < 16; ++i) {
      const int ds = wv + 4 * i;
      const float4 a = *(const float4*)(src + ds * 16);
      const float4 c = *(const float4*)(src + ds * 16 + 4);
      const float f[8] = {a.x*scl, a.y*scl, a.z*scl, a.w*scl,
                          c.x*scl, c.y*scl, c.z*scl, c.w*scl};
      *(int4v*)(dst + (size_t)ds * 512) = __builtin_bit_cast(int4v, pack8(f));
    }
  } else {
    const int bid = blockIdx.x - 512;
    const int b   = bid >> 7;
    const int kb  = (bid >> 2) & 31;
    const int db  = bid & 3;
    const int k0 = kb * 64, d0 = db * 256;
    {
      const int f = threadIdx.x & 63;
      const int r0 = threadIdx.x >> 6;
      #pragma unroll
      for (int i = 0; i < 16; ++i) {
        const int kloc = r0 + 4 * i;
        const float4 v4 = *(const float4*)(V + ((size_t)(b * TB + k0 + kloc)) * DD + d0 + f * 4);
        *(float4*)(t + kloc * 260 + f * 4) = v4;
      }
    }
    __syncthreads();
    const int lt  = threadIdx.x & 63;
    const int lo5 = lt & 31, hi = lt >> 5;
    const int kk  = threadIdx.x >> 6;
    #pragma unroll
    for (int dd = 0; dd < 8; ++dd) {
      float f[8];
      #pragma unroll
      for (int j = 0; j < 8; ++j)
        f[j] = t[(kk * 16 + hi * 8 + j) * 260 + dd * 32 + lo5];
      unsigned short* dst = Vf +
          (((size_t)(b * 32 + (d0 >> 5) + dd) * 128 + (k0 >> 4) + kk) * 64 + lt) * 8;
      *(int4v*)dst = __builtin_bit_cast(int4v, pack8(f));
    }
  }
}

// Non-draining barrier: LDS visibility only, keeps VMEM loads in flight.
__device__ __forceinline__ void lds_barrier() {
  __builtin_amdgcn_sched_barrier(0);
  asm volatile("s_waitcnt lgkmcnt(0)");
  __builtin_amdgcn_s_barrier();
  __builtin_amdgcn_sched_barrier(0);
}

// ===================== main kernel v10: v9 pipeline + LDS<80KB (2 blocks/CU) =======
// Grid 512: block = (b, qt 0..63, key-half h), heaviest qt dispatched first.
// QK: wave w owns keys [k0+32w, +32), full d; Q from LDS, K asm-pipelined.
// PV: wave w owns d slice [128w, +128); P 8KB, two 128-key phases; V asm-pipelined,
//     prologue issued before softmax. Barriers never drain vmcnt.
__global__ __launch_bounds__(512, 2)
void fa_fwd_f32_v10(const unsigned short* __restrict__ Qf, const int* __restrict__ AM,
                    const unsigned short* __restrict__ Kf, const unsigned short* __restrict__ Vf,
                    unsigned short* __restrict__ OA, unsigned short* __restrict__ OB,
                    float* __restrict__ ML)
{
  __shared__ __align__(16) unsigned short lds_Q[64 * 64 * 8];   // 65536 B [ds][lane][8]
  __shared__ __align__(16) unsigned short lds_P[8 * 64 * 8];    // 8192 B [slot][lane][8]
  __shared__ float lds_red[8][32];                              // 1024 B
  __shared__ unsigned char lds_nib[512];                        // pad-mask nibbles
  __shared__ int lds_tvi;                                       // total ~75.3 KB -> 2 blk/CU

  const int tid  = threadIdx.x;
  const int w    = tid >> 6;
  const int lane = tid & 63;
  const int lo5  = lane & 31;
  const int hi   = lane >> 5;

  const int bid  = blockIdx.x;
  const int xcd  = bid & 7, slot = bid >> 3;       // slot 0..63
  const int b    = xcd >> 1, x = xcd & 1;
  const int rank = slot >> 1, h = slot & 1;
  const int qt   = 63 - 2 * rank - x;              // heavy-first LPT
  const int q0   = qt << 5;

  // ---- stage Q tile (frag order, contiguous) + pad-mask nibbles ----
  {
    const char* qsrc = (const char*)Qf + ((size_t)(b * 64 + qt)) * 65536 + tid * 16;
    #pragma unroll
    for (int i = 0; i < 8; ++i)
      *(int4v*)((char*)lds_Q + tid * 16 + i * 8192) = *(const int4v*)(qsrc + (size_t)i * 8192);
  }
  if (tid == 0) lds_tvi = 0;
  __syncthreads();
  {
    const int4v mi = *(const int4v*)(AM + b * TB + 4 * tid);
    const unsigned char nib = (mi.x?1:0)|(mi.y?2:0)|(mi.z?4:0)|(mi.w?8:0);
    lds_nib[tid] = nib;
    if (nib) atomicOr(&lds_tvi, 1 << (tid >> 6));
  }
  __syncthreads();
  const int tvbits = lds_tvi;

  float m = -1e30f, l = 0.f;
  f32x16 oacc[4] = {f32x16{}, f32x16{}, f32x16{}, f32x16{}};

  const char* vb = (const char*)Vf + ((size_t)(b * 32 + 4 * w)) * 131072 + lane * 16;
  const int q = q0 + lo5;
  const int diag_kt = qt >> 3;

  const int nkt = diag_kt + 1;
  for (int kt = h; kt < nkt; kt += 2) {
    if (!(tvbits & (1 << kt))) continue;
    const int k0 = kt << 8;

    // ---- QK^T swapped, 16-deep asm K pipeline (counted vmcnt, never drained) ----
    f32x16 s0{}, s1{};
    {
      const char* kp = (const char*)Kf + ((size_t)(b * 64 + kt * 8 + w)) * 65536 + lane * 16;
      const char* qp = (const char*)lds_Q + lane * 16;
      int4v kb[16];
      #pragma unroll
      for (int i = 0; i < 16; ++i)
        asm volatile("global_load_dwordx4 %0, %1, off"
                     : "=v"(kb[i]) : "v"(kp + (size_t)i * 1024));
      __builtin_amdgcn_s_setprio(1);
      #pragma unroll
      for (int g = 0; g < 8; ++g) {
        if (g < 7) asm volatile("s_waitcnt vmcnt(8)");
        else       asm volatile("s_waitcnt vmcnt(0)");
        __builtin_amdgcn_sched_barrier(0);
        #pragma unroll
        for (int j = 0; j < 8; j += 2) {
          const int ds = 8 * g + j;
          s0 = __builtin_amdgcn_mfma_f32_32x32x16_bf16(
              __builtin_bit_cast(bf16x8, kb[ds & 15]),
              *(const bf16x8*)(qp + (size_t)ds * 1024), s0, 0, 0, 0);
          s1 = __builtin_amdgcn_mfma_f32_32x32x16_bf16(
              __builtin_bit_cast(bf16x8, kb[(ds + 1) & 15]),
              *(const bf16x8*)(qp + (size_t)(ds + 1) * 1024), s1, 0, 0, 0);
        }
        if (g < 6) {
          #pragma unroll
          for (int j = 0; j < 8; ++j) {
            const int dsn = 8 * (g + 2) + j;
            asm volatile("global_load_dwordx4 %0, %1, off"
                         : "=v"(kb[dsn & 15]) : "v"(kp + (size_t)dsn * 1024));
          }
        }
      }
      __builtin_amdgcn_s_setprio(0);
    }

    // ---- issue V prologue NOW: latency hides under softmax + barriers ----
    int4v vbv[16];
    {
      const char* vt = vb + (size_t)kt * 16384;
      #pragma unroll
      for (int i = 0; i < 16; ++i)
        asm volatile("global_load_dwordx4 %0, %1, off"
                     : "=v"(vbv[i])
                     : "v"(vt + (size_t)(i >> 2) * 1024 + (size_t)(i & 3) * 131072));
    }

    // ---- merge chains, mask (fast path off-diagonal), wave max ----
    u32 mw;
    {
      const u32* nw = (const u32*)(lds_nib + 64 * kt + 8 * w);
      const u32 n0 = nw[0], n1 = nw[1];
      mw = (n0 & 0xFu) | ((n0 >> 4) & 0xF0u) | ((n0 >> 8) & 0xF00u) | ((n0 >> 12) & 0xF000u);
      mw |= ((n1 & 0xFu) | ((n1 >> 4) & 0xF0u) | ((n1 >> 8) & 0xF00u) | ((n1 >> 12) & 0xF000u)) << 16;
    }
    float s[16];
    float mx = -1e30f;
    if (kt != diag_kt && mw == 0xffffffffu) {
      #pragma unroll
      for (int r = 0; r < 16; ++r) { s[r] = s0[r] + s1[r]; mx = fmaxf(mx, s[r]); }
    } else {
      #pragma unroll
      for (int r = 0; r < 16; ++r) {
        const int kl = (r & 3) + 8 * (r >> 2) + 4 * hi;
        const bool ok = (((mw >> kl) & 1u) != 0u) && (k0 + 32 * w + kl <= q);
        s[r] = ok ? (s0[r] + s1[r]) : -1e30f;
        mx = fmaxf(mx, s[r]);
      }
    }
    mx = fmaxf(mx, __shfl_xor(mx, 32, 64));
    if (lane < 32) lds_red[w][lo5] = mx;
    lds_barrier();                                     // BAR1: maxes + PV(t-1) done

    float gm = m;
    #pragma unroll
    for (int j = 0; j < 8; ++j) gm = fmaxf(gm, lds_red[j][lo5]);
    const float sc = __expf(m - gm);
    m = gm;
    const float pm = fmaxf(gm, -1e28f);                // all-masked guard
    float ls = 0.f;
    #pragma unroll
    for (int r = 0; r < 16; ++r) { s[r] = __expf(s[r] - pm); ls += s[r]; }
    ls += __shfl_xor(ls, 32, 64);
    l = l * sc + ls;
    #pragma unroll
    for (int nb = 0; nb < 4; ++nb)
      #pragma unroll
      for (int r = 0; r < 16; ++r) oacc[nb][r] *= sc;

    // P^T frag write: section-local slot 2*(w&3)+c (w<4 -> kcg 0..7; w>=4 -> 8..15)
    #define WRITE_P()                                                          \
    {                                                                          \
      _Pragma("unroll")                                                        \
      for (int c = 0; c < 2; ++c) {                                            \
        const u32 pw0 = pack2(s[8*c+1], s[8*c+0]);                             \
        const u32 pw1 = pack2(s[8*c+3], s[8*c+2]);                             \
        const u32 pw2 = pack2(s[8*c+5], s[8*c+4]);                             \
        const u32 pw3 = pack2(s[8*c+7], s[8*c+6]);                             \
        const u32 px0 = (u32)__shfl_xor((int)pw0, 32, 64);                     \
        const u32 px1 = (u32)__shfl_xor((int)pw1, 32, 64);                     \
        const u32 px2 = (u32)__shfl_xor((int)pw2, 32, 64);                     \
        const u32 px3 = (u32)__shfl_xor((int)pw3, 32, 64);                     \
        int4v f;                                                               \
        if (hi) { f.x=(int)px2; f.y=(int)px3; f.z=(int)pw2; f.w=(int)pw3; }    \
        else    { f.x=(int)pw0; f.y=(int)pw1; f.z=(int)px0; f.w=(int)px1; }    \
        *(int4v*)((char*)lds_P + ((2*(w&3) + c) * 64 + lane) * 16) = f;        \
      }                                                                        \
    }

    if (w < 4) WRITE_P();                              // keys [k0, k0+128)
    lds_barrier();                                     // BAR2: P phase-0 ready

    // ---- PV: 16-deep asm V pipeline, two 128-key phases ----
    {
      const char* vt = vb + (size_t)kt * 16384;
      __builtin_amdgcn_s_setprio(1);
      #pragma unroll
      for (int g = 0; g < 8; ++g) {
        if (g == 4) {
          __builtin_amdgcn_s_setprio(0);
          lds_barrier();                               // BAR3: PV phase-0 reads done
          if (w >= 4) WRITE_P();                       // keys [k0+128, k0+256)
          lds_barrier();                               // BAR4: P phase-1 ready
          __builtin_amdgcn_s_setprio(1);
        }
        if (g < 7) asm volatile("s_waitcnt vmcnt(8)");
        else       asm volatile("s_waitcnt vmcnt(0)");
        __builtin_amdgcn_sched_barrier(0);
        #pragma unroll
        for (int kk = 0; kk < 2; ++kk) {
          const int kcg = 2 * g + kk;                  // global key-chunk 0..15
          const int ps  = kcg & 7;                     // section-local P slot
          const bf16x8 pb = *(const bf16x8*)((const char*)lds_P + (ps * 64 + lane) * 16);
          #pragma unroll
          for (int nb = 0; nb < 4; ++nb) {
            const int idx = kcg * 4 + nb;
            oacc[nb] = __builtin_amdgcn_mfma_f32_32x32x16_bf16(
                __builtin_bit_cast(bf16x8, vbv[idx & 15]), pb, oacc[nb], 0, 0, 0);
          }
        }
        if (g < 6) {
          #pragma unroll
          for (int j = 0; j < 8; ++j) {
            const int idxn = 8 * (g + 2) + j;
            asm volatile("global_load_dwordx4 %0, %1, off"
                         : "=v"(vbv[idxn & 15])
                         : "v"(vt + (size_t)(idxn >> 2) * 1024 + (size_t)(idxn & 3) * 131072));
          }
        }
      }
      __builtin_amdgcn_s_setprio(0);
    }
    #undef WRITE_P
  }

  // ---- epilogue: lane-32 exchange -> 16B q-major bf16 stores ----
  {
    unsigned short* obase = (h ? OB : OA) + ((size_t)(b * TB + q0 + lo5)) * DD + 128 * w;
    #pragma unroll
    for (int nb = 0; nb < 4; ++nb) {
      #pragma unroll
      for (int m2 = 0; m2 < 4; ++m2) {
        const u32 e0 = pack2(oacc[nb][4*m2+1], oacc[nb][4*m2+0]);
        const u32 e1 = pack2(oacc[nb][4*m2+3], oacc[nb][4*m2+2]);
        const u32 y0 = (u32)__shfl_xor((int)e0, 32, 64);
        const u32 y1 = (u32)__shfl_xor((int)e1, 32, 64);
        if (hi == (nb >> 1)) {
          int4v f;
          if (hi) { f.x=(int)y0; f.y=(int)y1; f.z=(int)e0; f.w=(int)e1; }
          else    { f.x=(int)e0; f.y=(int)e1; f.z=(int)y0; f.w=(int)y1; }
          *(int4v*)(obase + 32 * nb + 8 * m2) = f;
        }
      }
    }
  }
  if (lane < 32) lds_red[w][lo5] = l;
  __syncthreads();
  if (w == 0 && lane < 32) {
    float lt = 0.f;
    #pragma unroll
    for (int j = 0; j < 8; ++j) lt += lds_red[j][lo5];
    const int row = b * TB + q0 + lo5;
    ML[h * 16384 + row] = m;
    ML[h * 16384 + 8192 + row] = lt;
  }
}

// ===================== merge: O = (eA*OA~ + eB*OB~) / (eA*lA + eB*lB) ================
__global__ __launch_bounds__(256)
void merge_v4(float* __restrict__ O, const unsigned short* __restrict__ OA,
              const unsigned short* __restrict__ OB, const float* __restrict__ ML) {
  const int idx = blockIdx.x * 256 + threadIdx.x;   // 16 elems per thread
  const int row = idx >> 6;
  const float mAv = ML[row],         lAv = ML[8192 + row];
  const float mBv = ML[16384 + row], lBv = ML[24576 + row];
  const float m = fmaxf(mAv, mBv);
  const float eA = __expf(mAv - m), eB = __expf(mBv - m);
  const float inv = 1.0f / (eA * lAv + eB * lBv);
  const float fa = eA * inv, fb = eB * inv;
  const uint4* pa = (const uint4*)(OA + (size_t)idx * 16);
  const uint4* pb = (const uint4*)(OB + (size_t)idx * 16);
  float4* od = (float4*)(O + (size_t)idx * 16);
  #pragma unroll
  for (int g = 0; g < 2; ++g) {
    const uint4 ua = pa[g], ub = pb[g];
    const u32 wa[4] = {ua.x, ua.y, ua.z, ua.w};
    const u32 wb[4] = {ub.x, ub.y, ub.z, ub.w};
    float out[8];
    #pragma unroll
    for (int i = 0; i < 4; ++i) {
      const float aLo = __uint_as_float(wa[i] << 16);
      const float aHi = __uint_as_float(wa[i] & 0xffff0000u);
      const float bLo = __uint_as_float(wb[i] << 16);
      const float bHi = __uint_as_float(wb[i] & 0xffff0000u);
      out[2*i]   = fa * aLo + fb * bLo;
      out[2*i+1] = fa * aHi + fb * bHi;
    }
    od[2*g]   = make_float4(out[0], out[1], out[2], out[3]);
    od[2*g+1] = make_float4(out[4], out[5], out[6], out[7]);
  }
}

// ===================== fallback (v1, known good, no workspace) ======================
__global__ __launch_bounds__(512, 2)
void fa_fwd_f32_v1(const float* __restrict__ Q, const float* __restrict__ K,
                   const float* __restrict__ V, const int* __restrict__ AM,
                   float* __restrict__ O)
{
  __shared__ __align__(16) float lds_part[8][32 * 68];
  __shared__ __align__(16) unsigned short lds_Pf[32][72];
  __shared__ float lds_m[32], lds_l[32], lds_scale[32];
  __shared__ unsigned lds_mask32[TB / 4];
  __shared__ int lds_tv[32];

  const int tid  = threadIdx.x;
  const int w    = tid >> 6;
  const int lane = tid & 63;
  const int lo5  = lane & 31;
  const int hi   = lane >> 5;

  const int bid  = blockIdx.x;
  const int xcd  = bid & 7;
  const int slot = bid >> 3;
  const int b    = xcd >> 1;
  const int half = xcd & 1;
  const int qt   = half ? (16 + slot) : (slot < 16 ? slot : 32 + slot);
  const int q0   = qt << 5;

  const int4v mi = *(const int4v*)(AM + b * TB + 4 * tid);
  const unsigned mw = (mi.x ? 1u : 0u) | (mi.y ? 0x100u : 0u) |
                      (mi.z ? 0x10000u : 0u) | (mi.w ? 0x1000000u : 0u);
  lds_mask32[tid] = mw;
  if (tid < 32) { lds_tv[tid] = 0; lds_m[tid] = -1e30f; lds_l[tid] = 0.0f; }
  __syncthreads();
  if (mw) lds_tv[tid >> 4] = 1;

  bf16x8 qf[8];
  {
    const float* qrow = Q + ((size_t)b * TB + q0 + lo5) * DD + w * 128 + hi * 8;
    #pragma unroll
    for (int kk = 0; kk < 8; ++kk) {
      const float4 a = *(const float4*)(qrow + kk * 16);
      const float4 c = *(const float4*)(qrow + kk * 16 + 4);
      const float f[8] = {a.x * 0.03125f, a.y * 0.03125f, a.z * 0.03125f, a.w * 0.03125f,
                          c.x * 0.03125f, c.y * 0.03125f, c.z * 0.03125f, c.w * 0.03125f};
      qf[kk] = pack8(f);
    }
  }

  f32x16 oacc[4] = {f32x16{}, f32x16{}, f32x16{}, f32x16{}};
  const float* kbat = K + (size_t)b * TB * DD + w * 128 + hi * 8;
  const float* vbat = V + (size_t)b * TB * DD + w * 128;
  __syncthreads();

  const int nkt = (qt >> 1) + 1;
  for (int kt = 0; kt < nkt; ++kt) {
    if (!lds_tv[kt]) continue;
    const int k0 = kt << 6;
    f32x16 s0{}, s1{};
    const float* kb0 = kbat + (size_t)(k0 + lo5) * DD;
    #pragma unroll
    for (int kk = 0; kk < 8; ++kk) {
      const float4 a0 = *(const float4*)(kb0 + kk * 16);
      const float4 a1 = *(const float4*)(kb0 + kk * 16 + 4);
      const float f0[8] = {a0.x, a0.y, a0.z, a0.w, a1.x, a1.y, a1.z, a1.w};
      s0 = __builtin_amdgcn_mfma_f32_32x32x16_bf16(qf[kk], pack8(f0), s0, 0, 0, 0);
      const float4 c0 = *(const float4*)(kb0 + (size_t)32 * DD + kk * 16);
      const float4 c1 = *(const float4*)(kb0 + (size_t)32 * DD + kk * 16 + 4);
      const float f1[8] = {c0.x, c0.y, c0.z, c0.w, c1.x, c1.y, c1.z, c1.w};
      s1 = __builtin_amdgcn_mfma_f32_32x32x16_bf16(qf[kk], pack8(f1), s1, 0, 0, 0);
    }
    {
      float* wp = lds_part[w];
      const int pos = lo5 + (hi << 5);
      #pragma unroll
      for (int r = 0; r < 16; ++r) {
        wp[r * 68 + pos]        = s0[r];
        wp[(16 + r) * 68 + pos] = s1[r];
      }
    }
    __syncthreads();
    {
      const int r = tid >> 4, g = tid & 15;
      const int regp  = (r & 3) | (((r >> 3) & 3) << 2);
      const int plane = ((g >> 3) << 4) + regp;
      const int pos   = ((4 * g) & 31) + (((r >> 2) & 1) << 5);
      float s[4] = {0.f, 0.f, 0.f, 0.f};
      #pragma unroll
      for (int ww = 0; ww < 8; ++ww) {
        const float4 v4 = *(const float4*)&lds_part[ww][plane * 68 + pos];
        s[0] += v4.x; s[1] += v4.y; s[2] += v4.z; s[3] += v4.w;
      }
      const unsigned mv = lds_mask32[(k0 >> 2) + g];
      const int qq = q0 + r;
      #pragma unroll
      for (int i = 0; i < 4; ++i) {
        const int kg = k0 + 4 * g + i;
        const bool ok = (((mv >> (8 * i)) & 0xffu) != 0u) && (kg <= qq);
        if (!ok) s[i] = -1e30f;
      }
      float mx = fmaxf(fmaxf(s[0], s[1]), fmaxf(s[2], s[3]));
      #pragma unroll
      for (int d = 1; d < 16; d <<= 1) mx = fmaxf(mx, __shfl_xor(mx, d, 64));
      const float mold = lds_m[r];
      const float mnew = fmaxf(mold, mx);
      float p[4], lsv = 0.f;
      #pragma unroll
      for (int i = 0; i < 4; ++i) { p[i] = __expf(s[i] - mnew); lsv += p[i]; }
      #pragma unroll
      for (int d = 1; d < 16; d <<= 1) lsv += __shfl_xor(lsv, d, 64);
      const float resc = __expf(mold - mnew);
      if (g == 0) {
        lds_m[r]     = mnew;
        lds_l[r]     = lds_l[r] * resc + lsv;
        lds_scale[r] = resc;
      }
      unsigned* pp = (unsigned*)&lds_Pf[r][4 * g];
      pp[0] = pack2(p[1], p[0]);
      pp[1] = pack2(p[3], p[2]);
    }
    __syncthreads();
    {
      float scv[16];
      #pragma unroll
      for (int reg = 0; reg < 16; ++reg)
        scv[reg] = lds_scale[(reg & 3) + ((reg >> 2) << 3) + (hi << 2)];
      #pragma unroll
      for (int nb = 0; nb < 4; ++nb) {
        #pragma unroll
        for (int reg = 0; reg < 16; ++reg) oacc[nb][reg] *= scv[reg];
      }
      bf16x8 pf[4];
      #pragma unroll
      for (int kc = 0; kc < 4; ++kc)
        pf[kc] = __builtin_bit_cast(bf16x8, *(const int4v*)&lds_Pf[lo5][kc * 16 + hi * 8]);
      const float* vbp = vbat + (size_t)k0 * DD + lo5;
      #pragma unroll
      for (int kc = 0; kc < 4; ++kc) {
        const float* vr = vbp + (size_t)(kc * 16 + hi * 8) * DD;
        float fv[4][8];
        #pragma unroll
        for (int j = 0; j < 8; ++j) {
          const float* vrj = vr + (size_t)j * DD;
          #pragma unroll
          for (int nb = 0; nb < 4; ++nb) fv[nb][j] = vrj[nb * 32];
        }
        #pragma unroll
        for (int nb = 0; nb < 4; ++nb)
          oacc[nb] = __builtin_amdgcn_mfma_f32_32x32x16_bf16(pf[kc], pack8(fv[nb]), oacc[nb], 0, 0, 0);
      }
    }
    __syncthreads();
  }

  float il[16];
  #pragma unroll
  for (int reg = 0; reg < 16; ++reg)
    il[reg] = 1.0f / lds_l[(reg & 3) + ((reg >> 2) << 3) + (hi << 2)];
  float* ob = O + ((size_t)b * TB + q0) * DD + w * 128;
  #pragma unroll
  for (int nb = 0; nb < 4; ++nb) {
    #pragma unroll
    for (int reg = 0; reg < 16; ++reg) {
      const int row = (reg & 3) + ((reg >> 2) << 3) + (hi << 2);
      ob[(size_t)row * DD + nb * 32 + lo5] = oacc[nb][reg] * il[reg];
    }
  }
}

extern "C" void kernel_launch(void* const* d_in, const int* in_sizes, int n_in,
                              void* d_out, int out_size, void* d_ws, size_t ws_size,
                              hipStream_t stream) {
  const float* Q  = (const float*)d_in[0];
  const float* K  = (const float*)d_in[1];
  const float* V  = (const float*)d_in[2];
  const int*   AM = (const int*)d_in[3];
  float* O = (float*)d_out;
  (void)in_sizes; (void)n_in; (void)out_size;

  const size_t SZ = 16777216;                 // each of Kf/Vf/Qf/OA/OB
  const size_t need = 5 * SZ + 131072;        // + ML
  if (ws_size >= need) {
    unsigned short* Kf = (unsigned short*)d_ws;
    unsigned short* Vf = (unsigned short*)((char*)d_ws + SZ);
    unsigned short* Qf = (unsigned short*)((char*)d_ws + 2 * SZ);
    unsigned short* OA = (unsigned short*)((char*)d_ws + 3 * SZ);
    unsigned short* OB = (unsigned short*)((char*)d_ws + 4 * SZ);
    float*          ML = (float*)((char*)d_ws + 5 * SZ);
    hipLaunchKernelGGL(conv_all, dim3(1024), dim3(256), 0, stream, Q, K, V, Qf, Kf, Vf);
    hipLaunchKernelGGL(fa_fwd_f32_v10, dim3(512), dim3(512), 0, stream,
                       Qf, AM, Kf, Vf, OA, OB, ML);
    hipLaunchKernelGGL(merge_v4, dim3(2048), dim3(256), 0, stream, O, OA, OB, ML);
  } else {
    hipLaunchKernelGGL(fa_fwd_f32_v1, dim3(256), dim3(512), 0, stream, Q, K, V, AM, O);
  }
}